// Round 3
// baseline (378.750 us; speedup 1.0000x reference)
//
#include <hip/hip_runtime.h>

// SuperLoRAGroup: out = FWHT24( G * Pi( FWHT24( pad( sign * vec(Bw@A)/16 ) ) ) )
// FWHT1 output periodic with period 2^22 => gather table W = 16MB only.
//
// P1: GEMM+sign fused, FWHT bits 0..13 per 16K chunk             -> ws (16MB)
// P2: FWHT bits 14..21 (256-pt, stride 2^14), in-place on ws
// P3: z[j] = ws[perm[j]&m]*G[j]*2^-24, FWHT bits 0..13           -> d_out
//     gathers phase-partitioned into 4x 4MB W-quarters; each quarter is
//     prefetched as coalesced streams (XCD-aware slice assignment) so the
//     random gathers hit L2 instead of demand-missing to HBM.
// P4: FWHT bits 14..23 in ONE pass: per column tile, 4 top-segments are
//     mid-transformed sequentially (results held in regs), then radix-4
//     combined across segments. 128MB traffic instead of 256MB.

#define THREADS 1024

typedef float vf4 __attribute__((ext_vector_type(4)));
typedef int vi4 __attribute__((ext_vector_type(4)));

constexpr float kScaling = 0.0625f;             // alpha/rank = 1/16
constexpr float kNorm = 5.9604644775390625e-8f; // 2^-24 (both fwht norms)

__device__ __forceinline__ void fwht16(float r[16]) {
#pragma unroll
  for (int s = 1; s < 16; s <<= 1) {
#pragma unroll
    for (int i = 0; i < 16; i++) {
      if (!(i & s)) {
        float a = r[i];
        float b = r[i | s];
        r[i] = a + b;
        r[i | s] = a - b;
      }
    }
  }
}

// FWHT over the 14 low bits of a 16384-float LDS tile (radix 16/16/16/4).
// Final round streams results straight to dst4. Caller syncs after fill.
template <bool NT>
__device__ __forceinline__ void fwht_lo_rounds(float* lds, int t, vf4* dst4) {
  vf4* lds4 = (vf4*)lds;
  {
    float r[16];
#pragma unroll
    for (int q = 0; q < 4; q++) {
      vf4 v = lds4[t * 4 + q];
#pragma unroll
      for (int c = 0; c < 4; c++) r[4 * q + c] = v[c];
    }
    fwht16(r);
#pragma unroll
    for (int q = 0; q < 4; q++) {
      vf4 v;
#pragma unroll
      for (int c = 0; c < 4; c++) v[c] = r[4 * q + c];
      lds4[t * 4 + q] = v;
    }
  }
  __syncthreads();
  {
    const int c = (t & 15) | ((t >> 4) << 8);
    float r[16];
#pragma unroll
    for (int k = 0; k < 16; k++) r[k] = lds[c + (k << 4)];
    fwht16(r);
#pragma unroll
    for (int k = 0; k < 16; k++) lds[c + (k << 4)] = r[k];
  }
  __syncthreads();
  {
    const int c = (t & 255) | ((t >> 8) << 12);
    float r[16];
#pragma unroll
    for (int k = 0; k < 16; k++) r[k] = lds[c + (k << 8)];
    fwht16(r);
#pragma unroll
    for (int k = 0; k < 16; k++) lds[c + (k << 8)] = r[k];
  }
  __syncthreads();
  {
    vf4 v0 = lds4[t + 0 * 1024];
    vf4 v1 = lds4[t + 1 * 1024];
    vf4 v2 = lds4[t + 2 * 1024];
    vf4 v3 = lds4[t + 3 * 1024];
    vf4 e0 = v0 + v1, e1 = v0 - v1;
    vf4 e2 = v2 + v3, e3 = v2 - v3;
    vf4 o0 = e0 + e2, o1 = e1 + e3, o2 = e0 - e2, o3 = e1 - e3;
    if (NT) {
      __builtin_nontemporal_store(o0, &dst4[t + 0 * 1024]);
      __builtin_nontemporal_store(o1, &dst4[t + 1 * 1024]);
      __builtin_nontemporal_store(o2, &dst4[t + 2 * 1024]);
      __builtin_nontemporal_store(o3, &dst4[t + 3 * 1024]);
    } else {
      dst4[t + 0 * 1024] = o0;
      dst4[t + 1 * 1024] = o1;
      dst4[t + 2 * 1024] = o2;
      dst4[t + 3 * 1024] = o3;
    }
  }
}

// P1: delta=(Bw@A)/16, *sign, FWHT bits0..13 -> W. 256 blocks.
__global__ __launch_bounds__(THREADS) void k1_build_fwht_lo(
    const float* __restrict__ A, const float* __restrict__ Bw,
    const float* __restrict__ sgn, float* __restrict__ W) {
  __shared__ float lds[16384];
  const int t = threadIdx.x;
  const int blk = blockIdx.x;
  const unsigned base = (unsigned)blk << 14;

  float a0[16], a1[16];
#pragma unroll
  for (int k = 0; k < 16; k++) {
    a0[k] = A[k * 2048 + t];
    a1[k] = A[k * 2048 + t + 1024];
  }
  const int r0 = blk * 8;
#pragma unroll
  for (int rl = 0; rl < 8; rl++) {
    float s0 = 0.f, s1 = 0.f;
#pragma unroll
    for (int k = 0; k < 16; k++) {
      float b = Bw[(r0 + rl) * 16 + k];
      s0 += b * a0[k];
      s1 += b * a1[k];
    }
    const int l0 = rl * 2048 + t;
    const int l1 = l0 + 1024;
    lds[l0] = s0 * kScaling * sgn[base + l0];
    lds[l1] = s1 * kScaling * sgn[base + l1];
  }
  __syncthreads();
  fwht_lo_rounds<false>(lds, t, (vf4*)W + ((unsigned)blk << 12));
}

// P2: 256-pt FWHT over bits 14..21 on W (2^22 floats), in-place. 256 blocks.
__global__ __launch_bounds__(THREADS) void k2_fwht_mid(float* __restrict__ W) {
  __shared__ float lds[16384];
  vf4* lds4 = (vf4*)lds;
  const int t = threadIdx.x;
  const int c0 = blockIdx.x * 16; // float4-column base
  vf4* B4 = (vf4*)W;              // 256 rows x 4096 f4-cols
#pragma unroll
  for (int m = 0; m < 4; m++) {
    const int idx4 = t + THREADS * m;
    const int row = idx4 >> 4, c4 = idx4 & 15;
    lds4[idx4] = B4[row * 4096 + c0 + c4];
  }
  __syncthreads();
  const int c4 = t & 15;
  const int f = t >> 4; // 0..63
#pragma unroll
  for (int r = 0; r < 4; r++) {
    const int m = 1 << (2 * r);
    int rows[4];
#pragma unroll
    for (int k2 = 0; k2 < 4; k2++)
      rows[k2] = (f & (m - 1)) + k2 * m + (f >> (2 * r)) * (m << 2);
    vf4 v0 = lds4[rows[0] * 16 + c4];
    vf4 v1 = lds4[rows[1] * 16 + c4];
    vf4 v2 = lds4[rows[2] * 16 + c4];
    vf4 v3 = lds4[rows[3] * 16 + c4];
    vf4 e0 = v0 + v1, e1 = v0 - v1;
    vf4 e2 = v2 + v3, e3 = v2 - v3;
    vf4 o0 = e0 + e2, o1 = e1 + e3, o2 = e0 - e2, o3 = e1 - e3;
    if (r < 3) {
      lds4[rows[0] * 16 + c4] = o0;
      lds4[rows[1] * 16 + c4] = o1;
      lds4[rows[2] * 16 + c4] = o2;
      lds4[rows[3] * 16 + c4] = o3;
      __syncthreads();
    } else {
      B4[rows[0] * 4096 + c0 + c4] = o0;
      B4[rows[1] * 4096 + c0 + c4] = o1;
      B4[rows[2] * 4096 + c0 + c4] = o2;
      B4[rows[3] * 4096 + c0 + c4] = o3;
    }
  }
}

// P3: z = W[perm&mask]*G*2^-24, FWHT bits0..13 -> out. 1024 blocks.
// Phase-partitioned gathers + coalesced quarter prefetch (XCD-aware ranks).
__global__ __launch_bounds__(THREADS) void k3_perm_fwht_lo(
    const float* __restrict__ W, const int* __restrict__ perm,
    const float* __restrict__ G, float* __restrict__ out) {
  __shared__ float lds[16384];
  const int t = threadIdx.x;
  const unsigned base4 = (unsigned)blockIdx.x << 12;
  const vi4* P4 = (const vi4*)perm + base4;
  const vf4* G4 = (const vf4*)G + base4;
  int src[16];
  float gg[16];
#pragma unroll
  for (int m = 0; m < 4; m++) {
    const int idx4 = t + THREADS * m;
    vi4 p = __builtin_nontemporal_load(&P4[idx4]);
    vf4 g = __builtin_nontemporal_load(&G4[idx4]);
#pragma unroll
    for (int c = 0; c < 4; c++) {
      src[4 * m + c] = p[c] & 0x3FFFFF;
      gg[4 * m + c] = g[c] * kNorm;
    }
  }
  // Prefetch slice assignment: with round-robin block->XCD dispatch,
  // blocks 8k..8k+7 sit on the 8 XCDs; rank k streams the same 64KB slice
  // of each quarter into every XCD's L2. Values are sunk after the loop.
  const unsigned rank = (blockIdx.x >> 3) & 63; // 64 ranks cover 4MB quarter
  const vf4* Wq = (const vf4*)W;
  float acc = 0.f;
  {
    const unsigned s0 = rank * 4096u + (unsigned)t; // quarter 0 slice
#pragma unroll
    for (int i = 0; i < 4; i++) {
      vf4 v = Wq[s0 + 1024u * i];
      acc += v[0] + v[1] + v[2] + v[3];
    }
  }
#pragma unroll
  for (int pass = 0; pass < 4; pass++) {
#pragma unroll
    for (int s = 0; s < 16; s++) {
      if ((src[s] >> 20) == pass) {
        lds[4 * (t + THREADS * (s >> 2)) + (s & 3)] = W[src[s]] * gg[s];
      }
    }
    if (pass < 3) { // stream next quarter while this one is consumed
      const unsigned sb =
          ((unsigned)(pass + 1) << 18) + rank * 4096u + (unsigned)t;
#pragma unroll
      for (int i = 0; i < 4; i++) {
        vf4 v = Wq[sb + 1024u * i];
        acc += v[0] + v[1] + v[2] + v[3];
      }
    }
    __syncthreads(); // keep resident blocks phase-aligned on the same quarter
  }
  asm volatile("" ::"v"(acc)); // keep prefetch loads alive
  fwht_lo_rounds<true>(lds, t, (vf4*)out + base4);
}

// P4: FWHT bits 14..23 in one pass. 512 blocks x 512 threads.
// Column tile = 8 f4 (128B) x 256 mid-rows = 32KB LDS; 4 top segments done
// sequentially (post-mid values kept in regs), then radix-4 across segments.
__global__ __launch_bounds__(512, 4) void k4_fwht_hi(float* __restrict__ out) {
  __shared__ float lds[8192]; // 2048 f4 = 32KB
  vf4* lds4 = (vf4*)lds;
  const int t = threadIdx.x;
  const unsigned c0 = (unsigned)blockIdx.x * 8; // f4-col base (4096 f4-cols)
  vf4* O4 = (vf4*)out;
  const int c4 = t & 7;
  const int f = t >> 3; // 0..63
  vf4 keep[4][4];
  vf4 ld[4];
#pragma unroll
  for (int m = 0; m < 4; m++) { // preload segment 0
    const int idx4 = t + 512 * m;
    ld[m] = O4[(unsigned)(idx4 >> 3) * 4096u + c0 + (unsigned)(idx4 & 7)];
  }
  for (int s = 0; s < 4; s++) {
#pragma unroll
    for (int m = 0; m < 4; m++) lds4[t + 512 * m] = ld[m];
    __syncthreads();
    if (s < 3) { // software-pipelined load of next segment
      const unsigned sb = ((unsigned)(s + 1)) << 20;
#pragma unroll
      for (int m = 0; m < 4; m++) {
        const int idx4 = t + 512 * m;
        ld[m] =
            O4[sb + (unsigned)(idx4 >> 3) * 4096u + c0 + (unsigned)(idx4 & 7)];
      }
    }
#pragma unroll
    for (int r = 0; r < 4; r++) { // 256-pt FWHT over mid bits
      const int m = 1 << (2 * r);
      int rows[4];
#pragma unroll
      for (int k2 = 0; k2 < 4; k2++)
        rows[k2] = (f & (m - 1)) + k2 * m + (f >> (2 * r)) * (m << 2);
      vf4 v0 = lds4[rows[0] * 8 + c4];
      vf4 v1 = lds4[rows[1] * 8 + c4];
      vf4 v2 = lds4[rows[2] * 8 + c4];
      vf4 v3 = lds4[rows[3] * 8 + c4];
      vf4 e0 = v0 + v1, e1 = v0 - v1;
      vf4 e2 = v2 + v3, e3 = v2 - v3;
      vf4 o0 = e0 + e2, o1 = e1 + e3, o2 = e0 - e2, o3 = e1 - e3;
      if (r < 3) {
        lds4[rows[0] * 8 + c4] = o0;
        lds4[rows[1] * 8 + c4] = o1;
        lds4[rows[2] * 8 + c4] = o2;
        lds4[rows[3] * 8 + c4] = o3;
        __syncthreads();
      } else { // rows[k2] = f + 64*k2
        keep[s][0] = o0;
        keep[s][1] = o1;
        keep[s][2] = o2;
        keep[s][3] = o3;
      }
    }
    __syncthreads(); // all reads of this tile done before next overwrite
  }
#pragma unroll
  for (int k2 = 0; k2 < 4; k2++) { // radix-4 over top segments
    vf4 v0 = keep[0][k2], v1 = keep[1][k2], v2 = keep[2][k2], v3 = keep[3][k2];
    vf4 e0 = v0 + v1, e1 = v0 - v1;
    vf4 e2 = v2 + v3, e3 = v2 - v3;
    const unsigned base = (unsigned)(f + 64 * k2) * 4096u + c0 + (unsigned)c4;
    __builtin_nontemporal_store(e0 + e2, &O4[base + (0u << 20)]);
    __builtin_nontemporal_store(e1 + e3, &O4[base + (1u << 20)]);
    __builtin_nontemporal_store(e0 - e2, &O4[base + (2u << 20)]);
    __builtin_nontemporal_store(e1 - e3, &O4[base + (3u << 20)]);
  }
}

extern "C" void kernel_launch(void* const* d_in, const int* in_sizes, int n_in,
                              void* d_out, int out_size, void* d_ws,
                              size_t ws_size, hipStream_t stream) {
  (void)in_sizes;
  (void)n_in;
  (void)out_size;
  (void)ws_size;
  const float* A = (const float*)d_in[0];   // (16, 2048)
  const float* Bw = (const float*)d_in[1];  // (2048, 16)
  const float* G = (const float*)d_in[2];   // (2^24,)
  const float* sgn = (const float*)d_in[3]; // (2^24,)
  const int* perm = (const int*)d_in[4];    // (2^24,) int32
  float* out = (float*)d_out;               // (2^24,) f32
  float* W = (float*)d_ws;                  // 2^22 floats = 16MB scratch

  k1_build_fwht_lo<<<256, THREADS, 0, stream>>>(A, Bw, sgn, W);
  k2_fwht_mid<<<256, THREADS, 0, stream>>>(W);
  k3_perm_fwht_lo<<<1024, THREADS, 0, stream>>>(W, perm, G, out);
  k4_fwht_hi<<<512, 512, 0, stream>>>(out);
}

// Round 4
// 366.207 us; speedup vs baseline: 1.0343x; 1.0343x over previous
//
#include <hip/hip_runtime.h>

// SuperLoRAGroup: out = FWHT24( G * Pi( FWHT24( pad( sign * vec(Bw@A)/16 ) ) ) )
// FWHT1 output periodic with period 2^22 => gather table W = 16MB only.
//
// P1 : GEMM+sign fused, FWHT bits 0..13 per 16K chunk            -> ws (16MB)
// P2 : FWHT bits 14..21 on ws as TWO register-radix-16 stream passes
//      (high-bit butterflies are lane-coalesced: 1KB/wave per load).
// P3 : z[j] = ws[perm[j]&m]*G[j]*2^-24, FWHT bits 0..13          -> d_out
//      gathers phase-partitioned into 4x 4MB W-quarters (L2-resident);
//      perm/G nontemporal loads, out nontemporal stores (protect L2's W).
// P4 : FWHT bits 14..23 on d_out as TWO register-radix-32 stream passes
//      (bits 14..18, then 19..23); pass A temporal (L3 hands data to pass
//      B), pass B stores nontemporal (final).

#define THREADS 1024

typedef float vf4 __attribute__((ext_vector_type(4)));
typedef int vi4 __attribute__((ext_vector_type(4)));

constexpr float kScaling = 0.0625f;             // alpha/rank = 1/16
constexpr float kNorm = 5.9604644775390625e-8f; // 2^-24 (both fwht norms)

__device__ __forceinline__ void fwht16(float r[16]) {
#pragma unroll
  for (int s = 1; s < 16; s <<= 1) {
#pragma unroll
    for (int i = 0; i < 16; i++) {
      if (!(i & s)) {
        float a = r[i];
        float b = r[i | s];
        r[i] = a + b;
        r[i | s] = a - b;
      }
    }
  }
}

// FWHT over the 14 low bits of a 16384-float LDS tile (radix 16/16/16/4).
// Final round streams results straight to dst4. Caller syncs after fill.
template <bool NT>
__device__ __forceinline__ void fwht_lo_rounds(float* lds, int t, vf4* dst4) {
  vf4* lds4 = (vf4*)lds;
  {
    float r[16];
#pragma unroll
    for (int q = 0; q < 4; q++) {
      vf4 v = lds4[t * 4 + q];
#pragma unroll
      for (int c = 0; c < 4; c++) r[4 * q + c] = v[c];
    }
    fwht16(r);
#pragma unroll
    for (int q = 0; q < 4; q++) {
      vf4 v;
#pragma unroll
      for (int c = 0; c < 4; c++) v[c] = r[4 * q + c];
      lds4[t * 4 + q] = v;
    }
  }
  __syncthreads();
  {
    const int c = (t & 15) | ((t >> 4) << 8);
    float r[16];
#pragma unroll
    for (int k = 0; k < 16; k++) r[k] = lds[c + (k << 4)];
    fwht16(r);
#pragma unroll
    for (int k = 0; k < 16; k++) lds[c + (k << 4)] = r[k];
  }
  __syncthreads();
  {
    const int c = (t & 255) | ((t >> 8) << 12);
    float r[16];
#pragma unroll
    for (int k = 0; k < 16; k++) r[k] = lds[c + (k << 8)];
    fwht16(r);
#pragma unroll
    for (int k = 0; k < 16; k++) lds[c + (k << 8)] = r[k];
  }
  __syncthreads();
  {
    vf4 v0 = lds4[t + 0 * 1024];
    vf4 v1 = lds4[t + 1 * 1024];
    vf4 v2 = lds4[t + 2 * 1024];
    vf4 v3 = lds4[t + 3 * 1024];
    vf4 e0 = v0 + v1, e1 = v0 - v1;
    vf4 e2 = v2 + v3, e3 = v2 - v3;
    vf4 o0 = e0 + e2, o1 = e1 + e3, o2 = e0 - e2, o3 = e1 - e3;
    if (NT) {
      __builtin_nontemporal_store(o0, &dst4[t + 0 * 1024]);
      __builtin_nontemporal_store(o1, &dst4[t + 1 * 1024]);
      __builtin_nontemporal_store(o2, &dst4[t + 2 * 1024]);
      __builtin_nontemporal_store(o3, &dst4[t + 3 * 1024]);
    } else {
      dst4[t + 0 * 1024] = o0;
      dst4[t + 1 * 1024] = o1;
      dst4[t + 2 * 1024] = o2;
      dst4[t + 3 * 1024] = o3;
    }
  }
}

// P1: delta=(Bw@A)/16, *sign, FWHT bits0..13 -> W. 256 blocks.
__global__ __launch_bounds__(THREADS) void k1_build_fwht_lo(
    const float* __restrict__ A, const float* __restrict__ Bw,
    const float* __restrict__ sgn, float* __restrict__ W) {
  __shared__ float lds[16384];
  const int t = threadIdx.x;
  const int blk = blockIdx.x;
  const unsigned base = (unsigned)blk << 14;

  float a0[16], a1[16];
#pragma unroll
  for (int k = 0; k < 16; k++) {
    a0[k] = A[k * 2048 + t];
    a1[k] = A[k * 2048 + t + 1024];
  }
  const int r0 = blk * 8;
#pragma unroll
  for (int rl = 0; rl < 8; rl++) {
    float s0 = 0.f, s1 = 0.f;
#pragma unroll
    for (int k = 0; k < 16; k++) {
      float b = Bw[(r0 + rl) * 16 + k];
      s0 += b * a0[k];
      s1 += b * a1[k];
    }
    const int l0 = rl * 2048 + t;
    const int l1 = l0 + 1024;
    lds[l0] = s0 * kScaling * sgn[base + l0];
    lds[l1] = s1 * kScaling * sgn[base + l1];
  }
  __syncthreads();
  fwht_lo_rounds<false>(lds, t, (vf4*)W + ((unsigned)blk << 12));
}

// Register-radix stream FWHT pass over one high-bit group.
// Butterfly axis: RADIX=2^RLOG values, partner stride = 2^LOWLOG float4s.
// Lanes stay contiguous in the low bits -> every load/store is 1KB/wave.
template <int RLOG, int LOWLOG, bool NTST>
__global__ __launch_bounds__(256) void k_stream_fwht(float* __restrict__ buf) {
  constexpr int R = 1 << RLOG;
  vf4* B4 = (vf4*)buf;
  const unsigned idx = blockIdx.x * 256u + threadIdx.x;
  const unsigned low = idx & ((1u << LOWLOG) - 1u);
  const unsigned high = idx >> LOWLOG;
  const unsigned base = (high << (LOWLOG + RLOG)) | low;
  vf4 r[R];
#pragma unroll
  for (int m = 0; m < R; m++) r[m] = B4[base + ((unsigned)m << LOWLOG)];
#pragma unroll
  for (int s = 1; s < R; s <<= 1) {
#pragma unroll
    for (int i = 0; i < R; i++) {
      if (!(i & s)) {
        vf4 a = r[i], b = r[i | s];
        r[i] = a + b;
        r[i | s] = a - b;
      }
    }
  }
#pragma unroll
  for (int m = 0; m < R; m++) {
    if (NTST)
      __builtin_nontemporal_store(r[m], &B4[base + ((unsigned)m << LOWLOG)]);
    else
      B4[base + ((unsigned)m << LOWLOG)] = r[m];
  }
}

// P3: z = W[perm&mask]*G*2^-24, FWHT bits0..13 -> out. 1024 blocks.
// Gathers phase-partitioned into 4x 4MB quarters of W for L2 residency.
__global__ __launch_bounds__(THREADS) void k3_perm_fwht_lo(
    const float* __restrict__ W, const int* __restrict__ perm,
    const float* __restrict__ G, float* __restrict__ out) {
  __shared__ float lds[16384];
  const int t = threadIdx.x;
  const unsigned base4 = (unsigned)blockIdx.x << 12;
  const vi4* P4 = (const vi4*)perm + base4;
  const vf4* G4 = (const vf4*)G + base4;
  int src[16];
  float gg[16];
#pragma unroll
  for (int m = 0; m < 4; m++) {
    const int idx4 = t + THREADS * m;
    vi4 p = __builtin_nontemporal_load(&P4[idx4]);
    vf4 g = __builtin_nontemporal_load(&G4[idx4]);
#pragma unroll
    for (int c = 0; c < 4; c++) {
      src[4 * m + c] = p[c] & 0x3FFFFF;
      gg[4 * m + c] = g[c] * kNorm;
    }
  }
#pragma unroll
  for (int pass = 0; pass < 4; pass++) {
#pragma unroll
    for (int s = 0; s < 16; s++) {
      if ((src[s] >> 20) == pass) {
        lds[4 * (t + THREADS * (s >> 2)) + (s & 3)] = W[src[s]] * gg[s];
      }
    }
    __syncthreads(); // keep resident blocks phase-aligned on the same quarter
  }
  fwht_lo_rounds<true>(lds, t, (vf4*)out + base4);
}

extern "C" void kernel_launch(void* const* d_in, const int* in_sizes, int n_in,
                              void* d_out, int out_size, void* d_ws,
                              size_t ws_size, hipStream_t stream) {
  (void)in_sizes;
  (void)n_in;
  (void)out_size;
  (void)ws_size;
  const float* A = (const float*)d_in[0];   // (16, 2048)
  const float* Bw = (const float*)d_in[1];  // (2048, 16)
  const float* G = (const float*)d_in[2];   // (2^24,)
  const float* sgn = (const float*)d_in[3]; // (2^24,)
  const int* perm = (const int*)d_in[4];    // (2^24,) int32
  float* out = (float*)d_out;               // (2^24,) f32
  float* W = (float*)d_ws;                  // 2^22 floats = 16MB scratch

  k1_build_fwht_lo<<<256, THREADS, 0, stream>>>(A, Bw, sgn, W);
  // P2: W is 2^20 float4s. bits 14..17 (f4-stride 2^12), bits 18..21 (2^16).
  k_stream_fwht<4, 12, false><<<256, 256, 0, stream>>>(W);
  k_stream_fwht<4, 16, false><<<256, 256, 0, stream>>>(W);
  k3_perm_fwht_lo<<<1024, THREADS, 0, stream>>>(W, perm, G, out);
  // P4: out is 2^22 float4s. bits 14..18 (f4-stride 2^12), bits 19..23 (2^17).
  k_stream_fwht<5, 12, false><<<512, 256, 0, stream>>>(out);
  k_stream_fwht<5, 17, true><<<512, 256, 0, stream>>>(out);
}